// Round 9
// baseline (250.911 us; speedup 1.0000x reference)
//
#include <hip/hip_runtime.h>

#define MARGIN 0.2f
#define LAMBDA_CONSISTENCY 0.1f
#define COS_EPS 1e-8f

#define B_DIM 8192
#define NTHR  1024
#define RPB   16
#define NBLK  (B_DIM / RPB)   // 512 blocks

// ---------------------------------------------------------------------------
// Fused pass — round-2 structure (empirically fastest; every manual
// vmcnt/LDS-DMA/reg-pipeline variant lost to the compiler's schedule).
// Per row k: load row k -> regs (thread t owns cols 4t..4t+3, 4096+4t..+3),
// load row ha[k] -> regs, stage row k in LDS, sync, ht-gather from LDS +
// column accumulators, row dot/norm -> wave partials, sync.
// NOTE: __launch_bounds__ has NO min-waves argument. Measured three times
// (R3: 32 VGPR + 273MB spills; R6: 64 VGPR + spills; R8: 32 VGPR + load
// serialization): the min-waves hint makes the allocator under-allocate ~2x
// and regresses. Unconstrained (R2/R7) the body fits ~40-90 VGPR, no spill.
// ---------------------------------------------------------------------------
__global__ __launch_bounds__(NTHR) void fused_pass_kernel(
    const float* __restrict__ S, const int* __restrict__ ha,
    const int* __restrict__ ht,
    float* __restrict__ dot_col, float* __restrict__ colsq,
    float* __restrict__ dot_row, float* __restrict__ rowsq) {
  __shared__ __align__(16) float lds[B_DIM];       // 32 KB staging
  __shared__ float redD[RPB * 16], redS[RPB * 16]; // 2 KB wave partials
  float4* lds4 = (float4*)lds;
  const int t = threadIdx.x;
  const int w = t >> 6, lane = t & 63;

  int4 h0 = ((const int4*)ht)[t];
  int4 h1 = ((const int4*)ht)[t + 1024];
  const int hti[8] = {h0.x, h0.y, h0.z, h0.w, h1.x, h1.y, h1.z, h1.w};

  float dacc[8] = {0.f, 0.f, 0.f, 0.f, 0.f, 0.f, 0.f, 0.f};
  float sacc[8] = {0.f, 0.f, 0.f, 0.f, 0.f, 0.f, 0.f, 0.f};

  const int k0 = blockIdx.x * RPB;

  for (int kk = 0; kk < RPB; ++kk) {
    const int k = k0 + kk;
    const float4* rowk = (const float4*)(S + (size_t)k * B_DIM);
    const float4* rowa = (const float4*)(S + (size_t)ha[k] * B_DIM);
    float4 a0 = rowk[t], a1 = rowk[t + 1024];
    float4 b0 = rowa[t], b1 = rowa[t + 1024];
    lds4[t] = a0;
    lds4[t + 1024] = a1;

    float d = a0.x * b0.x + a0.y * b0.y + a0.z * b0.z + a0.w * b0.w
            + a1.x * b1.x + a1.y * b1.y + a1.z * b1.z + a1.w * b1.w;
    float s = a0.x * a0.x + a0.y * a0.y + a0.z * a0.z + a0.w * a0.w
            + a1.x * a1.x + a1.y * a1.y + a1.z * a1.z + a1.w * a1.w;

    __syncthreads();  // staged row visible

    const float vv[8] = {a0.x, a0.y, a0.z, a0.w, a1.x, a1.y, a1.z, a1.w};
    float g[8];
#pragma unroll
    for (int c = 0; c < 8; ++c) g[c] = lds[hti[c]];  // random gather, ~2-way
#pragma unroll
    for (int c = 0; c < 8; ++c) {
      dacc[c] += vv[c] * g[c];
      sacc[c] += vv[c] * vv[c];
    }

#pragma unroll
    for (int o = 32; o > 0; o >>= 1) {
      d += __shfl_down(d, o, 64);
      s += __shfl_down(s, o, 64);
    }
    if (lane == 0) { redD[kk * 16 + w] = d; redS[kk * 16 + w] = s; }

    __syncthreads();  // LDS reuse guard (also covers redD/redS at end)
  }

  if (t < RPB) {  // block owns these rows: plain stores
    float dd = 0.f, ss = 0.f;
#pragma unroll
    for (int w2 = 0; w2 < 16; ++w2) {
      dd += redD[t * 16 + w2];
      ss += redS[t * 16 + w2];
    }
    dot_row[k0 + t] = dd;
    rowsq[k0 + t] = ss;
  }

#pragma unroll
  for (int c = 0; c < 4; ++c) {
    atomicAdd(&dot_col[4 * t + c], dacc[c]);
    atomicAdd(&colsq[4 * t + c], sacc[c]);
    atomicAdd(&dot_col[4096 + 4 * t + c], dacc[4 + c]);
    atomicAdd(&colsq[4096 + 4 * t + c], sacc[4 + c]);
  }
}

// ---------------------------------------------------------------------------
// Finalize stage 1: 32 blocks x 256 thr, one i per thread. Scattered gathers
// latency-hidden by 8192 parallel threads. Block partials -> 3 atomics.
// ---------------------------------------------------------------------------
__global__ __launch_bounds__(256) void finalize_partials(
    const float* __restrict__ S, const unsigned char* __restrict__ pmask,
    const int* __restrict__ ha, const int* __restrict__ ht,
    const float* __restrict__ dot_col, const float* __restrict__ colsq,
    const float* __restrict__ dot_row, const float* __restrict__ rowsq,
    float* __restrict__ scal) {
  const int t = threadIdx.x;
  const int i = blockIdx.x * 256 + t;

  const int a = ha[i];
  const int x = ht[i];
  const float m = pmask[(size_t)i * B_DIM + i] ? 1.f : 0.f;
  const float pos = S[(size_t)i * B_DIM + i];
  const float an  = S[(size_t)a * B_DIM + i];
  const float tn  = S[(size_t)i * B_DIM + x];

  float trip = fmaxf(MARGIN - pos + tn, 0.f) + fmaxf(MARGIN - pos + an, 0.f);
  const float cosA = dot_row[i] / fmaxf(sqrtf(rowsq[i]) * sqrtf(rowsq[a]), COS_EPS);
  const float cosT = dot_col[i] / fmaxf(sqrtf(colsq[i]) * sqrtf(colsq[x]), COS_EPS);
  float cons = fabsf(cosA - cosT);  // SIGMA_MARGIN = 0

  float cnt = m;
  trip *= m;
  cons *= m;

#pragma unroll
  for (int o = 32; o > 0; o >>= 1) {
    cnt  += __shfl_down(cnt, o, 64);
    trip += __shfl_down(trip, o, 64);
    cons += __shfl_down(cons, o, 64);
  }
  __shared__ float red[12];
  const int wid = t >> 6, lane = t & 63;
  if (lane == 0) { red[wid] = cnt; red[4 + wid] = trip; red[8 + wid] = cons; }
  __syncthreads();
  if (t == 0) {
    atomicAdd(&scal[0], red[0] + red[1] + red[2] + red[3]);
    atomicAdd(&scal[1], red[4] + red[5] + red[6] + red[7]);
    atomicAdd(&scal[2], red[8] + red[9] + red[10] + red[11]);
  }
}

// Finalize stage 2: assemble the 3 outputs.
__global__ void finalize_out(const float* __restrict__ scal,
                             float* __restrict__ out) {
  if (threadIdx.x == 0) {
    const float c = fmaxf(scal[0], 1.f);
    const float triplet = scal[1] / c;
    const float cons = scal[2] / c;
    out[0] = triplet + LAMBDA_CONSISTENCY * cons;
    out[1] = triplet;
    out[2] = cons;
  }
}

extern "C" void kernel_launch(void* const* d_in, const int* in_sizes, int n_in,
                              void* d_out, int out_size, void* d_ws, size_t ws_size,
                              hipStream_t stream) {
  const float* S = (const float*)d_in[0];
  const unsigned char* pmask = (const unsigned char*)d_in[1];  // jnp bool -> 1B
  const int* ha = (const int*)d_in[2];
  const int* ht = (const int*)d_in[3];

  float* ws = (float*)d_ws;
  float* dot_col = ws;
  float* colsq   = ws + B_DIM;
  float* scal    = ws + 2 * B_DIM;         // [cnt, trip, cons, pad]
  float* dot_row = ws + 2 * B_DIM + 4;
  float* rowsq   = ws + 3 * B_DIM + 4;

  // zero the atomic accumulators (dot_col, colsq, scal) in one memset
  hipMemsetAsync(ws, 0, (size_t)(2 * B_DIM + 4) * sizeof(float), stream);

  fused_pass_kernel<<<NBLK, NTHR, 0, stream>>>(
      S, ha, ht, dot_col, colsq, dot_row, rowsq);

  finalize_partials<<<B_DIM / 256, 256, 0, stream>>>(
      S, pmask, ha, ht, dot_col, colsq, dot_row, rowsq, scal);

  finalize_out<<<1, 64, 0, stream>>>(scal, (float*)d_out);
}

// Round 10
// 120.965 us; speedup vs baseline: 2.0742x; 2.0742x over previous
//
#include <hip/hip_runtime.h>

#define MARGIN 0.2f
#define LAMBDA_CONSISTENCY 0.1f
#define COS_EPS 1e-8f

#define B_DIM 8192

// ---------------------------------------------------------------------------
// Fused pass — VERBATIM round-2 kernel (measured: 183.7µs total with serial
// finalize => fused ~135-145µs). Do not "improve": R9's cleanup (compile-time
// unroll bound, regs-across-barrier, post-barrier shfl, end-of-kernel stores)
// regressed fused to ~235µs. Runtime rows_per_block => no full unroll;
// shfl-reduce BEFORE sync1 overlaps the staging wait; col values re-read from
// LDS => short live ranges.
// ---------------------------------------------------------------------------
__global__ __launch_bounds__(1024) void fused_pass_kernel(
    const float* __restrict__ S, const int* __restrict__ ha,
    const int* __restrict__ ht,
    float* __restrict__ dot_col, float* __restrict__ colsq,
    float* __restrict__ dot_row, float* __restrict__ rowsq,
    int B, int rows_per_block) {
  extern __shared__ float lds[];     // B floats staging + 32 reduction slots
  float* red = lds + B;
  const int t = threadIdx.x;

  float dacc[8], sacc[8];
  int hti[8];
#pragma unroll
  for (int c = 0; c < 8; ++c) {
    dacc[c] = 0.f;
    sacc[c] = 0.f;
    hti[c] = ht[t + 1024 * c];
  }

  const int k0 = blockIdx.x * rows_per_block;
  float4* lds4 = (float4*)lds;

  for (int k = k0; k < k0 + rows_per_block; ++k) {
    const float4* rowk = (const float4*)(S + (size_t)k * B);
    const float4* rowa = (const float4*)(S + (size_t)ha[k] * B);
    // 8192 floats = 2048 float4; 1024 threads x 2 coalesced float4 loads
    float4 a0 = rowk[t], a1 = rowk[t + 1024];
    float4 b0 = rowa[t], b1 = rowa[t + 1024];
    lds4[t] = a0;
    lds4[t + 1024] = a1;

    float d = a0.x * b0.x + a0.y * b0.y + a0.z * b0.z + a0.w * b0.w
            + a1.x * b1.x + a1.y * b1.y + a1.z * b1.z + a1.w * b1.w;
    float s = a0.x * a0.x + a0.y * a0.y + a0.z * a0.z + a0.w * a0.w
            + a1.x * a1.x + a1.y * a1.y + a1.z * a1.z + a1.w * a1.w;
#pragma unroll
    for (int o = 32; o > 0; o >>= 1) {
      d += __shfl_down(d, o, 64);
      s += __shfl_down(s, o, 64);
    }
    if ((t & 63) == 0) { red[t >> 6] = d; red[16 + (t >> 6)] = s; }
    __syncthreads();  // staging + red visible

#pragma unroll
    for (int c = 0; c < 8; ++c) {
      float v = lds[t + 1024 * c];  // stride-1 across lanes: conflict-free
      float g = lds[hti[c]];        // random gather within row (~2-way, free)
      dacc[c] += v * g;
      sacc[c] += v * v;
    }
    if (t == 0) {
      float dd = 0.f, ss = 0.f;
#pragma unroll
      for (int w = 0; w < 16; ++w) { dd += red[w]; ss += red[16 + w]; }
      dot_row[k] = dd;
      rowsq[k] = ss;
    }
    __syncthreads();  // before overwriting the staged row
  }

#pragma unroll
  for (int c = 0; c < 8; ++c) {
    atomicAdd(&dot_col[t + 1024 * c], dacc[c]);
    atomicAdd(&colsq[t + 1024 * c], sacc[c]);
  }
}

// ---------------------------------------------------------------------------
// Finalize stage 1: 32 blocks x 256 thr, one i per thread. Scattered gathers
// latency-hidden by 8192 parallel threads. Block partials -> 3 atomics.
// ---------------------------------------------------------------------------
__global__ __launch_bounds__(256) void finalize_partials(
    const float* __restrict__ S, const unsigned char* __restrict__ pmask,
    const int* __restrict__ ha, const int* __restrict__ ht,
    const float* __restrict__ dot_col, const float* __restrict__ colsq,
    const float* __restrict__ dot_row, const float* __restrict__ rowsq,
    float* __restrict__ scal) {
  const int t = threadIdx.x;
  const int i = blockIdx.x * 256 + t;

  const int a = ha[i];
  const int x = ht[i];
  const float m = pmask[(size_t)i * B_DIM + i] ? 1.f : 0.f;
  const float pos = S[(size_t)i * B_DIM + i];
  const float an  = S[(size_t)a * B_DIM + i];
  const float tn  = S[(size_t)i * B_DIM + x];

  float trip = fmaxf(MARGIN - pos + tn, 0.f) + fmaxf(MARGIN - pos + an, 0.f);
  const float cosA = dot_row[i] / fmaxf(sqrtf(rowsq[i]) * sqrtf(rowsq[a]), COS_EPS);
  const float cosT = dot_col[i] / fmaxf(sqrtf(colsq[i]) * sqrtf(colsq[x]), COS_EPS);
  float cons = fabsf(cosA - cosT);  // SIGMA_MARGIN = 0

  float cnt = m;
  trip *= m;
  cons *= m;

#pragma unroll
  for (int o = 32; o > 0; o >>= 1) {
    cnt  += __shfl_down(cnt, o, 64);
    trip += __shfl_down(trip, o, 64);
    cons += __shfl_down(cons, o, 64);
  }
  __shared__ float red[12];
  const int wid = t >> 6, lane = t & 63;
  if (lane == 0) { red[wid] = cnt; red[4 + wid] = trip; red[8 + wid] = cons; }
  __syncthreads();
  if (t == 0) {
    atomicAdd(&scal[0], red[0] + red[1] + red[2] + red[3]);
    atomicAdd(&scal[1], red[4] + red[5] + red[6] + red[7]);
    atomicAdd(&scal[2], red[8] + red[9] + red[10] + red[11]);
  }
}

// Finalize stage 2: assemble the 3 outputs.
__global__ void finalize_out(const float* __restrict__ scal,
                             float* __restrict__ out) {
  if (threadIdx.x == 0) {
    const float c = fmaxf(scal[0], 1.f);
    const float triplet = scal[1] / c;
    const float cons = scal[2] / c;
    out[0] = triplet + LAMBDA_CONSISTENCY * cons;
    out[1] = triplet;
    out[2] = cons;
  }
}

extern "C" void kernel_launch(void* const* d_in, const int* in_sizes, int n_in,
                              void* d_out, int out_size, void* d_ws, size_t ws_size,
                              hipStream_t stream) {
  const float* S = (const float*)d_in[0];
  const unsigned char* pmask = (const unsigned char*)d_in[1];  // jnp bool -> 1B
  const int* ha = (const int*)d_in[2];
  const int* ht = (const int*)d_in[3];
  const int B = in_sizes[2];  // 8192

  float* ws = (float*)d_ws;
  float* dot_col = ws;
  float* colsq   = ws + B_DIM;
  float* scal    = ws + 2 * B_DIM;         // [cnt, trip, cons, pad]
  float* dot_row = ws + 2 * B_DIM + 4;
  float* rowsq   = ws + 3 * B_DIM + 4;

  // zero the atomic accumulators (dot_col, colsq, scal) in one memset
  hipMemsetAsync(ws, 0, (size_t)(2 * B_DIM + 4) * sizeof(float), stream);

  const int blocks = 512;  // 16 rows/block at B=8192 (runtime bound: no unroll)
  fused_pass_kernel<<<blocks, 1024, (B_DIM + 32) * sizeof(float), stream>>>(
      S, ha, ht, dot_col, colsq, dot_row, rowsq, B, B / blocks);

  finalize_partials<<<B_DIM / 256, 256, 0, stream>>>(
      S, pmask, ha, ht, dot_col, colsq, dot_row, rowsq, scal);

  finalize_out<<<1, 64, 0, stream>>>(scal, (float*)d_out);
}

// Round 11
// 111.866 us; speedup vs baseline: 2.2430x; 1.0813x over previous
//
#include <hip/hip_runtime.h>

#define MARGIN 0.2f
#define LAMBDA_CONSISTENCY 0.1f
#define COS_EPS 1e-8f

#define B_DIM 8192

// ---------------------------------------------------------------------------
// Fused pass — round-10 body (measured 120.97µs total) with ONE change:
// double-buffered staging -> single barrier per row. Iter k stages into
// buf[k&1], gathers from buf[k&1]; buf[p] is next overwritten in iter k+2,
// which any wave reaches only after passing barrier(k+1), which requires all
// waves to have finished gather(k). So one barrier/row is safe, and fast
// waves issue row-(k+1) loads while slow waves still gather row k (the
// latency bubble R2 paid per row). No cross-iteration registers (R3/R4's
// spill/serialization failure mode): live set identical to R10.
// Keep VERBATIM otherwise: runtime rows_per_block (no unroll), shfl-reduce
// before the barrier, own-cols re-read from LDS, in-loop t0 row stores.
// ---------------------------------------------------------------------------
__global__ __launch_bounds__(1024) void fused_pass_kernel(
    const float* __restrict__ S, const int* __restrict__ ha,
    const int* __restrict__ ht,
    float* __restrict__ dot_col, float* __restrict__ colsq,
    float* __restrict__ dot_row, float* __restrict__ rowsq,
    int B, int rows_per_block) {
  extern __shared__ float lds[];     // 2*B staging + 2*32 reduction slots
  float* red = lds + 2 * B;          // red[2][32]
  const int t = threadIdx.x;

  float dacc[8], sacc[8];
  int hti[8];
#pragma unroll
  for (int c = 0; c < 8; ++c) {
    dacc[c] = 0.f;
    sacc[c] = 0.f;
    hti[c] = ht[t + 1024 * c];
  }

  const int k0 = blockIdx.x * rows_per_block;

  for (int k = k0; k < k0 + rows_per_block; ++k) {
    const int p = k & 1;
    float* buf = lds + (p ? B : 0);
    float4* buf4 = (float4*)buf;
    float* redk = red + (p << 5);

    const float4* rowk = (const float4*)(S + (size_t)k * B);
    const float4* rowa = (const float4*)(S + (size_t)ha[k] * B);
    // 8192 floats = 2048 float4; 1024 threads x 2 coalesced float4 loads
    float4 a0 = rowk[t], a1 = rowk[t + 1024];
    float4 b0 = rowa[t], b1 = rowa[t + 1024];
    buf4[t] = a0;
    buf4[t + 1024] = a1;

    float d = a0.x * b0.x + a0.y * b0.y + a0.z * b0.z + a0.w * b0.w
            + a1.x * b1.x + a1.y * b1.y + a1.z * b1.z + a1.w * b1.w;
    float s = a0.x * a0.x + a0.y * a0.y + a0.z * a0.z + a0.w * a0.w
            + a1.x * a1.x + a1.y * a1.y + a1.z * a1.z + a1.w * a1.w;
#pragma unroll
    for (int o = 32; o > 0; o >>= 1) {
      d += __shfl_down(d, o, 64);
      s += __shfl_down(s, o, 64);
    }
    if ((t & 63) == 0) { redk[t >> 6] = d; redk[16 + (t >> 6)] = s; }
    __syncthreads();  // staging + red visible (the ONLY barrier per row)

#pragma unroll
    for (int c = 0; c < 8; ++c) {
      float v = buf[t + 1024 * c];  // stride-1 across lanes: conflict-free
      float g = buf[hti[c]];        // random gather within row (~2-way, free)
      dacc[c] += v * g;
      sacc[c] += v * v;
    }
    if (t == 0) {
      float dd = 0.f, ss = 0.f;
#pragma unroll
      for (int w = 0; w < 16; ++w) { dd += redk[w]; ss += redk[16 + w]; }
      dot_row[k] = dd;
      rowsq[k] = ss;
    }
  }

#pragma unroll
  for (int c = 0; c < 8; ++c) {
    atomicAdd(&dot_col[t + 1024 * c], dacc[c]);
    atomicAdd(&colsq[t + 1024 * c], sacc[c]);
  }
}

// ---------------------------------------------------------------------------
// Finalize stage 1: 32 blocks x 256 thr, one i per thread. Scattered gathers
// latency-hidden by 8192 parallel threads. Block partials -> 3 atomics.
// ---------------------------------------------------------------------------
__global__ __launch_bounds__(256) void finalize_partials(
    const float* __restrict__ S, const unsigned char* __restrict__ pmask,
    const int* __restrict__ ha, const int* __restrict__ ht,
    const float* __restrict__ dot_col, const float* __restrict__ colsq,
    const float* __restrict__ dot_row, const float* __restrict__ rowsq,
    float* __restrict__ scal) {
  const int t = threadIdx.x;
  const int i = blockIdx.x * 256 + t;

  const int a = ha[i];
  const int x = ht[i];
  const float m = pmask[(size_t)i * B_DIM + i] ? 1.f : 0.f;
  const float pos = S[(size_t)i * B_DIM + i];
  const float an  = S[(size_t)a * B_DIM + i];
  const float tn  = S[(size_t)i * B_DIM + x];

  float trip = fmaxf(MARGIN - pos + tn, 0.f) + fmaxf(MARGIN - pos + an, 0.f);
  const float cosA = dot_row[i] / fmaxf(sqrtf(rowsq[i]) * sqrtf(rowsq[a]), COS_EPS);
  const float cosT = dot_col[i] / fmaxf(sqrtf(colsq[i]) * sqrtf(colsq[x]), COS_EPS);
  float cons = fabsf(cosA - cosT);  // SIGMA_MARGIN = 0

  float cnt = m;
  trip *= m;
  cons *= m;

#pragma unroll
  for (int o = 32; o > 0; o >>= 1) {
    cnt  += __shfl_down(cnt, o, 64);
    trip += __shfl_down(trip, o, 64);
    cons += __shfl_down(cons, o, 64);
  }
  __shared__ float red[12];
  const int wid = t >> 6, lane = t & 63;
  if (lane == 0) { red[wid] = cnt; red[4 + wid] = trip; red[8 + wid] = cons; }
  __syncthreads();
  if (t == 0) {
    atomicAdd(&scal[0], red[0] + red[1] + red[2] + red[3]);
    atomicAdd(&scal[1], red[4] + red[5] + red[6] + red[7]);
    atomicAdd(&scal[2], red[8] + red[9] + red[10] + red[11]);
  }
}

// Finalize stage 2: assemble the 3 outputs.
__global__ void finalize_out(const float* __restrict__ scal,
                             float* __restrict__ out) {
  if (threadIdx.x == 0) {
    const float c = fmaxf(scal[0], 1.f);
    const float triplet = scal[1] / c;
    const float cons = scal[2] / c;
    out[0] = triplet + LAMBDA_CONSISTENCY * cons;
    out[1] = triplet;
    out[2] = cons;
  }
}

extern "C" void kernel_launch(void* const* d_in, const int* in_sizes, int n_in,
                              void* d_out, int out_size, void* d_ws, size_t ws_size,
                              hipStream_t stream) {
  const float* S = (const float*)d_in[0];
  const unsigned char* pmask = (const unsigned char*)d_in[1];  // jnp bool -> 1B
  const int* ha = (const int*)d_in[2];
  const int* ht = (const int*)d_in[3];
  const int B = in_sizes[2];  // 8192

  float* ws = (float*)d_ws;
  float* dot_col = ws;
  float* colsq   = ws + B_DIM;
  float* scal    = ws + 2 * B_DIM;         // [cnt, trip, cons, pad]
  float* dot_row = ws + 2 * B_DIM + 4;
  float* rowsq   = ws + 3 * B_DIM + 4;

  // zero the atomic accumulators (dot_col, colsq, scal) in one memset
  hipMemsetAsync(ws, 0, (size_t)(2 * B_DIM + 4) * sizeof(float), stream);

  const int blocks = 512;  // 16 rows/block (runtime bound: no unroll)
  fused_pass_kernel<<<blocks, 1024, (2 * B_DIM + 64) * sizeof(float), stream>>>(
      S, ha, ht, dot_col, colsq, dot_row, rowsq, B, B / blocks);

  finalize_partials<<<B_DIM / 256, 256, 0, stream>>>(
      S, pmask, ha, ht, dot_col, colsq, dot_row, rowsq, scal);

  finalize_out<<<1, 64, 0, stream>>>(scal, (float*)d_out);
}

// Round 12
// 106.162 us; speedup vs baseline: 2.3635x; 1.0537x over previous
//
#include <hip/hip_runtime.h>

#define MARGIN 0.2f
#define LAMBDA_CONSISTENCY 0.1f
#define COS_EPS 1e-8f

#define B_DIM 8192
#define NBLK  512   // 16 rows/block, 2 blocks/CU
#define NPART NBLK

// ---------------------------------------------------------------------------
// Fused pass — R11 body (measured 111.9µs total) with ONE change: the column
// epilogue. If dpart!=nullptr, each block plain-stores its 8192 dot/sq
// partials (coalesced, no RMW) instead of 16K atomicAdds into a 512-way
// contended 64KB region. Fallback (dpart==nullptr) is the R11 atomic path,
// byte-identical. Everything else VERBATIM (runtime rows_per_block, one
// barrier/row via double buffer, shfl before barrier, LDS re-read of cols).
// ---------------------------------------------------------------------------
__global__ __launch_bounds__(1024) void fused_pass_kernel(
    const float* __restrict__ S, const int* __restrict__ ha,
    const int* __restrict__ ht,
    float* __restrict__ dot_col, float* __restrict__ colsq,
    float* __restrict__ dot_row, float* __restrict__ rowsq,
    float* __restrict__ dpart, float* __restrict__ spart,
    int B, int rows_per_block) {
  extern __shared__ float lds[];     // 2*B staging + 2*32 reduction slots
  float* red = lds + 2 * B;          // red[2][32]
  const int t = threadIdx.x;

  float dacc[8], sacc[8];
  int hti[8];
#pragma unroll
  for (int c = 0; c < 8; ++c) {
    dacc[c] = 0.f;
    sacc[c] = 0.f;
    hti[c] = ht[t + 1024 * c];
  }

  const int k0 = blockIdx.x * rows_per_block;

  for (int k = k0; k < k0 + rows_per_block; ++k) {
    const int p = k & 1;
    float* buf = lds + (p ? B : 0);
    float4* buf4 = (float4*)buf;
    float* redk = red + (p << 5);

    const float4* rowk = (const float4*)(S + (size_t)k * B);
    const float4* rowa = (const float4*)(S + (size_t)ha[k] * B);
    float4 a0 = rowk[t], a1 = rowk[t + 1024];
    float4 b0 = rowa[t], b1 = rowa[t + 1024];
    buf4[t] = a0;
    buf4[t + 1024] = a1;

    float d = a0.x * b0.x + a0.y * b0.y + a0.z * b0.z + a0.w * b0.w
            + a1.x * b1.x + a1.y * b1.y + a1.z * b1.z + a1.w * b1.w;
    float s = a0.x * a0.x + a0.y * a0.y + a0.z * a0.z + a0.w * a0.w
            + a1.x * a1.x + a1.y * a1.y + a1.z * a1.z + a1.w * a1.w;
#pragma unroll
    for (int o = 32; o > 0; o >>= 1) {
      d += __shfl_down(d, o, 64);
      s += __shfl_down(s, o, 64);
    }
    if ((t & 63) == 0) { redk[t >> 6] = d; redk[16 + (t >> 6)] = s; }
    __syncthreads();  // staging + red visible (the ONLY barrier per row)

#pragma unroll
    for (int c = 0; c < 8; ++c) {
      float v = buf[t + 1024 * c];  // stride-1 across lanes: conflict-free
      float g = buf[hti[c]];        // random gather within row (~2-way)
      dacc[c] += v * g;
      sacc[c] += v * v;
    }
    if (t == 0) {
      float dd = 0.f, ss = 0.f;
#pragma unroll
      for (int w = 0; w < 16; ++w) { dd += redk[w]; ss += redk[16 + w]; }
      dot_row[k] = dd;
      rowsq[k] = ss;
    }
  }

  if (dpart) {
    // plain-store partials: coalesced (consecutive t -> consecutive cols)
    float* dp = dpart + (size_t)blockIdx.x * B;
    float* sp = spart + (size_t)blockIdx.x * B;
#pragma unroll
    for (int c = 0; c < 8; ++c) {
      dp[t + 1024 * c] = dacc[c];
      sp[t + 1024 * c] = sacc[c];
    }
  } else {
#pragma unroll
    for (int c = 0; c < 8; ++c) {
      atomicAdd(&dot_col[t + 1024 * c], dacc[c]);
      atomicAdd(&colsq[t + 1024 * c], sacc[c]);
    }
  }
}

// ---------------------------------------------------------------------------
// Reduce partials: 128 blocks x 1024 thr. Block owns 64 columns; thread
// (chunk = t>>6, col = t&63) sums 32 partials; LDS tree over 16 chunks.
// Loads coalesced: lanes 0..63 read consecutive columns for each p.
// ---------------------------------------------------------------------------
__global__ __launch_bounds__(1024) void reduce_partials(
    const float* __restrict__ dpart, const float* __restrict__ spart,
    float* __restrict__ dot_col, float* __restrict__ colsq) {
  __shared__ float rd[16][64], rs[16][64];
  const int t = threadIdx.x;
  const int c = t & 63, chunk = t >> 6;
  const int col = blockIdx.x * 64 + c;

  float dd = 0.f, ss = 0.f;
  for (int p = chunk * 32; p < chunk * 32 + 32; ++p) {
    dd += dpart[(size_t)p * B_DIM + col];
    ss += spart[(size_t)p * B_DIM + col];
  }
  rd[chunk][c] = dd;
  rs[chunk][c] = ss;
  __syncthreads();
  if (t < 64) {
    float d2 = 0.f, s2 = 0.f;
#pragma unroll
    for (int q = 0; q < 16; ++q) { d2 += rd[q][t]; s2 += rs[q][t]; }
    dot_col[blockIdx.x * 64 + t] = d2;
    colsq[blockIdx.x * 64 + t] = s2;
  }
}

// ---------------------------------------------------------------------------
// Finalize stage 1: 32 blocks x 256 thr, one i per thread.
// ---------------------------------------------------------------------------
__global__ __launch_bounds__(256) void finalize_partials(
    const float* __restrict__ S, const unsigned char* __restrict__ pmask,
    const int* __restrict__ ha, const int* __restrict__ ht,
    const float* __restrict__ dot_col, const float* __restrict__ colsq,
    const float* __restrict__ dot_row, const float* __restrict__ rowsq,
    float* __restrict__ scal) {
  const int t = threadIdx.x;
  const int i = blockIdx.x * 256 + t;

  const int a = ha[i];
  const int x = ht[i];
  const float m = pmask[(size_t)i * B_DIM + i] ? 1.f : 0.f;
  const float pos = S[(size_t)i * B_DIM + i];
  const float an  = S[(size_t)a * B_DIM + i];
  const float tn  = S[(size_t)i * B_DIM + x];

  float trip = fmaxf(MARGIN - pos + tn, 0.f) + fmaxf(MARGIN - pos + an, 0.f);
  const float cosA = dot_row[i] / fmaxf(sqrtf(rowsq[i]) * sqrtf(rowsq[a]), COS_EPS);
  const float cosT = dot_col[i] / fmaxf(sqrtf(colsq[i]) * sqrtf(colsq[x]), COS_EPS);
  float cons = fabsf(cosA - cosT);  // SIGMA_MARGIN = 0

  float cnt = m;
  trip *= m;
  cons *= m;

#pragma unroll
  for (int o = 32; o > 0; o >>= 1) {
    cnt  += __shfl_down(cnt, o, 64);
    trip += __shfl_down(trip, o, 64);
    cons += __shfl_down(cons, o, 64);
  }
  __shared__ float red[12];
  const int wid = t >> 6, lane = t & 63;
  if (lane == 0) { red[wid] = cnt; red[4 + wid] = trip; red[8 + wid] = cons; }
  __syncthreads();
  if (t == 0) {
    atomicAdd(&scal[0], red[0] + red[1] + red[2] + red[3]);
    atomicAdd(&scal[1], red[4] + red[5] + red[6] + red[7]);
    atomicAdd(&scal[2], red[8] + red[9] + red[10] + red[11]);
  }
}

// Finalize stage 2: assemble the 3 outputs.
__global__ void finalize_out(const float* __restrict__ scal,
                             float* __restrict__ out) {
  if (threadIdx.x == 0) {
    const float c = fmaxf(scal[0], 1.f);
    const float triplet = scal[1] / c;
    const float cons = scal[2] / c;
    out[0] = triplet + LAMBDA_CONSISTENCY * cons;
    out[1] = triplet;
    out[2] = cons;
  }
}

extern "C" void kernel_launch(void* const* d_in, const int* in_sizes, int n_in,
                              void* d_out, int out_size, void* d_ws, size_t ws_size,
                              hipStream_t stream) {
  const float* S = (const float*)d_in[0];
  const unsigned char* pmask = (const unsigned char*)d_in[1];  // jnp bool -> 1B
  const int* ha = (const int*)d_in[2];
  const int* ht = (const int*)d_in[3];
  const int B = in_sizes[2];  // 8192

  float* ws = (float*)d_ws;
  float* dot_col = ws;
  float* colsq   = ws + B_DIM;
  float* scal    = ws + 2 * B_DIM;         // [cnt, trip, cons, pad]
  float* dot_row = ws + 2 * B_DIM + 4;
  float* rowsq   = ws + 3 * B_DIM + 4;

  // partials region (33.5 MB) after the base layout, 160KB-aligned offset
  const size_t part_off = 40960;           // floats
  const size_t need = (part_off + 2ULL * NPART * B_DIM) * sizeof(float);
  const bool use_part = ws_size >= need;
  float* dpart = use_part ? ws + part_off : nullptr;
  float* spart = use_part ? ws + part_off + (size_t)NPART * B_DIM : nullptr;

  if (use_part) {
    // only the 3 scalar accumulators need zeroing
    hipMemsetAsync(scal, 0, 4 * sizeof(float), stream);
  } else {
    // R11 fallback: zero dot_col, colsq, scal
    hipMemsetAsync(ws, 0, (size_t)(2 * B_DIM + 4) * sizeof(float), stream);
  }

  fused_pass_kernel<<<NBLK, 1024, (2 * B_DIM + 64) * sizeof(float), stream>>>(
      S, ha, ht, dot_col, colsq, dot_row, rowsq, dpart, spart, B, B / NBLK);

  if (use_part)
    reduce_partials<<<B_DIM / 64, 1024, 0, stream>>>(dpart, spart, dot_col, colsq);

  finalize_partials<<<B_DIM / 256, 256, 0, stream>>>(
      S, pmask, ha, ht, dot_col, colsq, dot_row, rowsq, scal);

  finalize_out<<<1, 64, 0, stream>>>(scal, (float*)d_out);
}